// Round 18
// baseline (188.138 us; speedup 1.0000x reference)
//
#include <hip/hip_runtime.h>
#include <hip/hip_fp16.h>
#include <math.h>
#include <string.h>

#define VOL   128
#define V2    (VOL*VOL)
#define V3    (VOL*VOL*VOL)
#define NPTS  262144
#define LATD  16
#define BATCH 8
#define FACTORF 64.0f
#define NBINS (VOL*VOL)
#define RZ 8
#define RY 8
#define HALO 13                 // RZ+5 (+-2 window + 2-voxel target span)
#define NRANGE (HALO*HALO)      // 169
#define TBL_CAP 4096
#define FAR_CAP 8192

// ws layout (bytes)
#define WS_HBUF   0u
#define WS_HIST   256u
#define WS_START  65792u
#define WS_RANK   131344u
#define WS_CTRL   1179920u
#define WS_FARBUF 1179952u
#define WS_COORDC 1311024u
#define WS_FULL   18088240u

__device__ __forceinline__ float bf16r(float x) {
    unsigned u = __float_as_uint(x);
    u = (u + 0x7fffu + ((u >> 16) & 1u)) & 0xffff0000u;
    return __uint_as_float(u);
}
__device__ __forceinline__ unsigned short f16bits(float v) {
    __half h = __float2half_rn(v);
    unsigned short us; memcpy(&us, &h, 2);
    return us;
}
__device__ __forceinline__ float f16val(unsigned short us) {
    __half h; memcpy(&h, &us, 2);
    return __half2float(h);
}

// SIREN MLP, per-op bf16 (verified round 11).
__global__ void mlp_kernel(const float* __restrict__ x,
                           const float* __restrict__ W0,
                           const float* __restrict__ b0,
                           const float* __restrict__ Wh,
                           const float* __restrict__ bh,
                           float* __restrict__ hout) {
    int b = threadIdx.x;
    if (b >= BATCH) return;
    float xb[LATD];
    #pragma unroll
    for (int i = 0; i < LATD; ++i) xb[i] = bf16r(x[b*LATD + i]);
    float h[8];
    #pragma unroll
    for (int j = 0; j < 8; ++j) {
        float acc = 0.f;
        #pragma unroll
        for (int i = 0; i < LATD; ++i) acc += xb[i] * bf16r(W0[i*8 + j]);
        float t = bf16r(acc);
        t = bf16r(t + bf16r(b0[j]));
        t = bf16r(30.0f * t);
        h[j] = bf16r(sinf(t));
    }
    for (int l = 0; l < 4; ++l) {
        float nh[8];
        #pragma unroll
        for (int j = 0; j < 8; ++j) {
            float acc = 0.f;
            #pragma unroll
            for (int r = 0; r < 8; ++r) acc += h[r] * bf16r(Wh[(l*8 + r)*8 + j]);
            float t = bf16r(acc);
            t = bf16r(t + bf16r(bh[l*8 + j]));
            float s = bf16r(sinf(t));
            nh[j] = bf16r(h[j] + s);
        }
        #pragma unroll
        for (int j = 0; j < 8; ++j) h[j] = nh[j];
    }
    #pragma unroll
    for (int j = 0; j < 8; ++j) hout[b*8 + j] = h[j];
}

__global__ __launch_bounds__(256) void hist_rank_kernel(const int* __restrict__ inds,
                                                        unsigned* __restrict__ hist,
                                                        unsigned* __restrict__ rank) {
    int n = blockIdx.x * 256 + threadIdx.x;
    if (n >= NPTS) return;
    rank[n] = atomicAdd(&hist[inds[n*3]*VOL + inds[n*3+1]], 1u);
}

__global__ __launch_bounds__(256) void scan_kernel(const unsigned* __restrict__ hist,
                                                   unsigned* __restrict__ binstart,
                                                   unsigned* __restrict__ ctrl) {
    __shared__ unsigned part[256];
    int t = threadIdx.x;
    const int CH = NBINS / 256;
    unsigned s = 0;
    for (int k = 0; k < CH; ++k) s += hist[t*CH + k];
    part[t] = s; __syncthreads();
    for (int off = 1; off < 256; off <<= 1) {
        unsigned v = (t >= off) ? part[t - off] : 0u;
        __syncthreads();
        part[t] += v;
        __syncthreads();
    }
    unsigned run = (t == 0) ? 0u : part[t - 1];
    for (int k = 0; k < CH; ++k) {
        int idx = t*CH + k;
        binstart[idx] = run;
        run += hist[idx];
    }
    if (t == 0) { binstart[NBINS] = NPTS; ctrl[0] = 0u; ctrl[1] = 0u; }
}

// 8-byte encoded entries, bin-sorted; far entries -> exact float4 sidebuf
// with cz biased by 256*b to carry the batch index.
__global__ __launch_bounds__(256) void coords_kernel(
    const float* __restrict__ Wf, const float* __restrict__ bfv_g,
    const float* __restrict__ rv, const int* __restrict__ inds,
    const float* __restrict__ hbuf, const unsigned* __restrict__ binstart,
    const unsigned* __restrict__ rank,
    unsigned* __restrict__ ctrl, float4* __restrict__ farbuf,
    ushort4* __restrict__ coords_c)
{
    __shared__ float hs[64];
    if (threadIdx.x < 64) hs[threadIdx.x] = hbuf[threadIdx.x];
    __syncthreads();
    int n = blockIdx.x * 256 + threadIdx.x;
    if (n >= NPTS) return;
    int iz = inds[n*3], iy = inds[n*3+1], ix = inds[n*3+2];
    float cnx = ((float)ix - FACTORF) / FACTORF;
    float cny = ((float)iy - FACTORF) / FACTORF;
    float cnz = ((float)iz - FACTORF) / FACTORF;
    float val0 = rv[n];
    float4 bfv = ((const float4*)bfv_g)[n];
    float4 wf[8];
    #pragma unroll
    for (int r = 0; r < 8; ++r)
        wf[r] = ((const float4*)(Wf + (size_t)r * 4 * NPTS))[n];
    unsigned pos = binstart[iz*VOL + iy] + rank[n];
    #pragma unroll
    for (int b = 0; b < BATCH; ++b) {
        float o0 = bfv.x, o1 = bfv.y, o2 = bfv.z, o3 = bfv.w;
        #pragma unroll
        for (int r = 0; r < 8; ++r) {
            float hv = hs[b*8 + r];
            o0 = fmaf(hv, wf[r].x, o0);
            o1 = fmaf(hv, wf[r].y, o1);
            o2 = fmaf(hv, wf[r].z, o2);
            o3 = fmaf(hv, wf[r].w, o3);
        }
        float cx = FACTORF * (cnx + o0) + FACTORF;
        float cy = FACTORF * (cny + o1) + FACTORF;
        float cz = FACTORF * (cnz + o2) + FACTORF;
        float val = val0 + o3;
        int bz = (int)floorf(cz), by = (int)floorf(cy);
        bool nearzy = ((unsigned)(bz - iz + 2) <= 4u) &&
                      ((unsigned)(by - iy + 2) <= 4u);
        ushort4 e;
        if (nearzy) {
            e.x = (unsigned short)fminf(fmaxf(fmaf(cx + 8.f, 256.f, 0.5f), 0.f), 65535.f);
            e.y = (unsigned short)fminf(fmaf(cy - (float)iy + 2.f, 8192.f, 0.5f), 40959.f);
            e.z = (unsigned short)fminf(fmaf(cz - (float)iz + 2.f, 8192.f, 0.5f), 40959.f);
            e.w = f16bits(val);
        } else {
            e.x = 0; e.y = 0xFFFFu; e.z = 0; e.w = 0;
            unsigned fp = atomicAdd(&ctrl[0], 1u);
            if (fp < FAR_CAP)
                farbuf[fp] = make_float4(cx, cy, cz + 256.0f * (float)b, val);
        }
        coords_c[(size_t)b * NPTS + pos] = e;
    }
}

// One wg = (batch, 8x8x128 region). Slot->entry LDS table, 8-way gathers.
__global__ __launch_bounds__(256) void region_kernel(
    const ushort4* __restrict__ coords_c,
    const unsigned* __restrict__ binstart, float* __restrict__ out)
{
    __shared__ float tile[RZ*RY*VOL];    // 32 KB
    __shared__ unsigned tbl[TBL_CAP];    // 16 KB
    __shared__ unsigned rcum[NRANGE+1];
    __shared__ int rbase[NRANGE];
    int tid = threadIdx.x;
    int b   = blockIdx.x >> 8;
    int rid = blockIdx.x & 255;
    int z0 = (rid >> 4) * RZ, y0 = (rid & 15) * RY;

    for (int i = tid; i < RZ*RY*VOL; i += 256) tile[i] = 0.f;

    unsigned rs = 0;
    if (tid < NRANGE) {
        int zi = tid / HALO, yi = tid - zi * HALO;
        int zz = (z0 - 3 + zi) & (VOL-1);
        int yy = (y0 - 3 + yi) & (VOL-1);
        int base = zz * VOL + yy;
        rs = binstart[base];
        rcum[tid+1] = binstart[base+1] - rs;
    }
    if (tid == 0) rcum[0] = 0u;
    __syncthreads();
    for (int off = 1; off < NRANGE; off <<= 1) {
        unsigned v = 0u;
        if (tid < NRANGE && tid >= off) v = rcum[tid+1-off];
        __syncthreads();
        if (tid < NRANGE && tid >= off) rcum[tid+1] += v;
        __syncthreads();
    }
    if (tid < NRANGE) rbase[tid] = (int)rs - (int)rcum[tid];
    __syncthreads();

    unsigned total = rcum[NRANGE];
    const ushort4* cb = coords_c + (size_t)b * NPTS;
    const int ox[8] = {0,1,0,0,0,1,1,1};
    const int oy[8] = {0,0,1,0,1,0,1,1};
    const int oz[8] = {0,0,0,1,1,1,0,1};

    for (unsigned c0 = 0; c0 < total; c0 += TBL_CAP) {
        unsigned c1 = (total - c0 < TBL_CAP) ? total : c0 + TBL_CAP;
        __syncthreads();
        if (tid < NRANGE) {
            unsigned lo = rcum[tid] > c0 ? rcum[tid] : c0;
            unsigned hi = rcum[tid+1] < c1 ? rcum[tid+1] : c1;
            int zi = tid / HALO, yi = tid - zi * HALO;
            unsigned meta = ((unsigned)zi << 22) | ((unsigned)yi << 26);
            int rb = rbase[tid];
            for (unsigned i = lo; i < hi; ++i)
                tbl[i - c0] = (unsigned)(rb + (int)i) | meta;
        }
        __syncthreads();
        unsigned nn = c1 - c0;
        for (unsigned f = tid; f < nn; f += 2048u) {
            ushort4 e[8]; unsigned t[8]; bool v[8];
            #pragma unroll
            for (int u = 0; u < 8; ++u) {
                unsigned fu = f + (unsigned)u * 256u;
                v[u] = fu < nn;
                if (v[u]) {
                    t[u] = tbl[fu];
                    e[u] = cb[t[u] & 0x3FFFFFu];
                }
            }
            #pragma unroll
            for (int u = 0; u < 8; ++u) {
                if (!v[u] || e[u].y == 0xFFFFu) continue;
                int zi = (int)((t[u] >> 22) & 15u), yi = (int)((t[u] >> 26) & 15u);
                int piz = (z0 - 3 + zi) & (VOL-1);
                int piy = (y0 - 3 + yi) & (VOL-1);
                float cx = (float)e[u].x * (1.f/256.f) - 8.f;
                float cy = (float)piy + (float)e[u].y * (1.f/8192.f) - 2.f;
                float cz = (float)piz + (float)e[u].z * (1.f/8192.f) - 2.f;
                float val = f16val(e[u].w);
                float fxf = floorf(cx), fyf = floorf(cy), fzf = floorf(cz);
                int bx = (int)fxf, by = (int)fyf, bz = (int)fzf;
                float fx = cx - fxf, fy = cy - fyf, fz = cz - fzf;
                float gx = 1.f - fx, gy = 1.f - fy, gz = 1.f - fz;
                float w[8] = {gx*gy*gz, fx*gy*gz, gx*fy*gz, gx*gy*fz,
                              gx*fy*fz, fx*gy*fz, fx*fy*gz, fx*fy*fz};
                #pragma unroll
                for (int o = 0; o < 8; ++o) {
                    int Z = (bz + oz[o]) & (VOL-1), dz = Z - z0;
                    if ((unsigned)dz >= RZ) continue;
                    int Y = (by + oy[o]) & (VOL-1), dy = Y - y0;
                    if ((unsigned)dy >= RY) continue;
                    int X = (bx + ox[o]) & (VOL-1);
                    atomicAdd(&tile[(dz << 10) + (dy << 7) + X], val * w[o]);
                }
            }
        }
    }
    __syncthreads();
    size_t ob = (size_t)b * V3;
    for (int i = tid; i < RZ*RY*VOL; i += 256) {
        int lz = i >> 10, ly = (i >> 7) & (RY-1), lx = i & 127;
        out[ob + (size_t)(z0+lz)*V2 + (y0+ly)*VOL + lx] = tile[i];
    }
}

// Far entries: cz carries 256*b bias.
__global__ __launch_bounds__(256) void far_kernel(
    const unsigned* __restrict__ ctrl, const float4* __restrict__ farbuf,
    float* __restrict__ out)
{
    unsigned cnt = ctrl[0];
    if (cnt > FAR_CAP) cnt = FAR_CAP;
    const int ox[8] = {0,1,0,0,0,1,1,1};
    const int oy[8] = {0,0,1,0,1,0,1,1};
    const int oz[8] = {0,0,0,1,1,1,0,1};
    for (unsigned idx = blockIdx.x * 256 + threadIdx.x; idx < cnt;
         idx += gridDim.x * 256) {
        float4 c = farbuf[idx];
        int b = (int)floorf((c.z + 8.0f) * (1.0f/256.0f));
        float cz = c.z - 256.0f * (float)b;
        float fxf = floorf(c.x), fyf = floorf(c.y), fzf = floorf(cz);
        int bx = (int)fxf, by = (int)fyf, bz = (int)fzf;
        float fx = c.x - fxf, fy = c.y - fyf, fz = cz - fzf;
        float gx = 1.f - fx, gy = 1.f - fy, gz = 1.f - fz;
        float val = c.w;
        float w[8] = {gx*gy*gz, fx*gy*gz, gx*fy*gz, gx*gy*fz,
                      gx*fy*fz, fx*gy*fz, fx*fy*gz, fx*fy*fz};
        float* ob = out + (size_t)b * V3;
        #pragma unroll
        for (int o = 0; o < 8; ++o) {
            int Z = (bz + oz[o]) & (VOL-1);
            int Y = (by + oy[o]) & (VOL-1);
            int X = (bx + ox[o]) & (VOL-1);
            atomicAdd(ob + (size_t)Z*V2 + Y*VOL + X, val * w[o]);
        }
    }
}

// Fallback (round-11 verified path) if workspace too small.
__global__ __launch_bounds__(256) void scatter_fallback(
    const float* __restrict__ Wf, const float* __restrict__ bfv_g,
    const float* __restrict__ rv, const int* __restrict__ inds,
    const float* __restrict__ hbuf, float* __restrict__ out)
{
    __shared__ float hs[BATCH*8];
    if (threadIdx.x < BATCH*8) hs[threadIdx.x] = hbuf[threadIdx.x];
    __syncthreads();
    int n = blockIdx.x * blockDim.x + threadIdx.x;
    if (n >= NPTS) return;
    int iz = inds[n*3 + 0], iy = inds[n*3 + 1], ix = inds[n*3 + 2];
    float cnx = ((float)ix - FACTORF) / FACTORF;
    float cny = ((float)iy - FACTORF) / FACTORF;
    float cnz = ((float)iz - FACTORF) / FACTORF;
    float val0 = rv[n];
    float4 bfv = ((const float4*)bfv_g)[n];
    float4 wf[8];
    #pragma unroll
    for (int r = 0; r < 8; ++r)
        wf[r] = ((const float4*)(Wf + (size_t)r * 4 * NPTS))[n];
    static const int offs[8][3] = {{0,0,0},{1,0,0},{0,1,0},{0,0,1},
                                   {0,1,1},{1,0,1},{1,1,0},{1,1,1}};
    #pragma unroll
    for (int b = 0; b < BATCH; ++b) {
        float o0 = bfv.x, o1 = bfv.y, o2 = bfv.z, o3 = bfv.w;
        #pragma unroll
        for (int r = 0; r < 8; ++r) {
            float hv = hs[b*8 + r];
            o0 = fmaf(hv, wf[r].x, o0);
            o1 = fmaf(hv, wf[r].y, o1);
            o2 = fmaf(hv, wf[r].z, o2);
            o3 = fmaf(hv, wf[r].w, o3);
        }
        float cx = FACTORF * (cnx + o0) + FACTORF;
        float cy = FACTORF * (cny + o1) + FACTORF;
        float cz = FACTORF * (cnz + o2) + FACTORF;
        float val = val0 + o3;
        float fxf = floorf(cx), fyf = floorf(cy), fzf = floorf(cz);
        int bx = (int)fxf, by = (int)fyf, bz = (int)fzf;
        float fx = cx - fxf, fy = cy - fyf, fz = cz - fzf;
        float gx = 1.f - fx, gy = 1.f - fy, gz = 1.f - fz;
        float w[8] = {gx*gy*gz, fx*gy*gz, gx*fy*gz, gx*gy*fz,
                      gx*fy*fz, fx*gy*fz, fx*fy*gz, fx*fy*fz};
        float* ob = out + (size_t)b * V3;
        #pragma unroll
        for (int o = 0; o < 8; ++o) {
            int X = (bx + offs[o][0]) & (VOL-1);
            int Y = (by + offs[o][1]) & (VOL-1);
            int Z = (bz + offs[o][2]) & (VOL-1);
            atomicAdd(ob + (size_t)Z*V2 + Y*VOL + X, val * w[o]);
        }
    }
}

extern "C" void kernel_launch(void* const* d_in, const int* in_sizes, int n_in,
                              void* d_out, int out_size, void* d_ws, size_t ws_size,
                              hipStream_t stream) {
    const float* x    = (const float*)d_in[0];
    const float* W0   = (const float*)d_in[1];
    const float* b0   = (const float*)d_in[2];
    const float* Wh   = (const float*)d_in[3];
    const float* bh   = (const float*)d_in[4];
    const float* Wf   = (const float*)d_in[5];
    const float* bf   = (const float*)d_in[6];
    const float* rv   = (const float*)d_in[7];
    const int*   inds = (const int*)d_in[8];
    float* out = (float*)d_out;
    char*  ws  = (char*)d_ws;

    float*    hbuf     = (float*)(ws + WS_HBUF);
    unsigned* hist     = (unsigned*)(ws + WS_HIST);
    unsigned* binstart = (unsigned*)(ws + WS_START);
    unsigned* rank     = (unsigned*)(ws + WS_RANK);
    unsigned* ctrl     = (unsigned*)(ws + WS_CTRL);
    float4*   farbuf   = (float4*)(ws + WS_FARBUF);
    ushort4*  coords_c = (ushort4*)(ws + WS_COORDC);

    mlp_kernel<<<1, 64, 0, stream>>>(x, W0, b0, Wh, bh, hbuf);

    if (ws_size >= (size_t)WS_FULL) {
        hipMemsetAsync(hist, 0, NBINS*4, stream);
        hist_rank_kernel<<<NPTS/256, 256, 0, stream>>>(inds, hist, rank);
        scan_kernel<<<1, 256, 0, stream>>>(hist, binstart, ctrl);
        coords_kernel<<<NPTS/256, 256, 0, stream>>>(Wf, bf, rv, inds, hbuf,
                                                    binstart, rank,
                                                    ctrl, farbuf, coords_c);
        region_kernel<<<256*BATCH, 256, 0, stream>>>(coords_c, binstart, out);
        far_kernel<<<8, 256, 0, stream>>>(ctrl, farbuf, out);
    } else {
        hipMemsetAsync(d_out, 0, (size_t)out_size * sizeof(float), stream);
        scatter_fallback<<<NPTS/256, 256, 0, stream>>>(Wf, bf, rv, inds, hbuf, out);
    }
}

// Round 19
// 176.237 us; speedup vs baseline: 1.0675x; 1.0675x over previous
//
#include <hip/hip_runtime.h>
#include <hip/hip_fp16.h>
#include <math.h>
#include <string.h>

#define VOL   128
#define V2    (VOL*VOL)
#define V3    (VOL*VOL*VOL)
#define NPTS  262144
#define LATD  16
#define BATCH 8
#define FACTORF 64.0f
#define NBINS (VOL*VOL)
#define RZ 8
#define RY 4
#define BG 4                     // batches per wg
#define HALO_Z (RZ+5)            // 13
#define HALO_Y (RY+5)            // 9
#define NRANGE (HALO_Z*HALO_Y)   // 117
#define FAR_CAP 8192

// ws layout (bytes)
#define WS_HBUF   0u
#define WS_HIST   256u          // 65536
#define WS_START  65792u        // 65540 -> pad
#define WS_RANK   131344u       // 1048576
#define WS_CTRL   1179920u      // 32
#define WS_WGSUM  1179952u      // 256
#define WS_FARBUF 1180208u      // 131072
#define WS_COORDC 1311280u      // NPTS*64 = 16777216
#define WS_FULL   18088496u

__device__ __forceinline__ float bf16r(float x) {
    unsigned u = __float_as_uint(x);
    u = (u + 0x7fffu + ((u >> 16) & 1u)) & 0xffff0000u;
    return __uint_as_float(u);
}
__device__ __forceinline__ unsigned f16bits(float v) {
    __half h = __float2half_rn(v);
    unsigned short us; memcpy(&us, &h, 2);
    return (unsigned)us;
}
__device__ __forceinline__ float f16val(unsigned us) {
    unsigned short u16 = (unsigned short)us;
    __half h; memcpy(&h, &u16, 2);
    return __half2float(h);
}

// SIREN MLP, per-op bf16 (verified round 11).
__global__ void mlp_kernel(const float* __restrict__ x,
                           const float* __restrict__ W0,
                           const float* __restrict__ b0,
                           const float* __restrict__ Wh,
                           const float* __restrict__ bh,
                           float* __restrict__ hout) {
    int b = threadIdx.x;
    if (b >= BATCH) return;
    float xb[LATD];
    #pragma unroll
    for (int i = 0; i < LATD; ++i) xb[i] = bf16r(x[b*LATD + i]);
    float h[8];
    #pragma unroll
    for (int j = 0; j < 8; ++j) {
        float acc = 0.f;
        #pragma unroll
        for (int i = 0; i < LATD; ++i) acc += xb[i] * bf16r(W0[i*8 + j]);
        float t = bf16r(acc);
        t = bf16r(t + bf16r(b0[j]));
        t = bf16r(30.0f * t);
        h[j] = bf16r(sinf(t));
    }
    for (int l = 0; l < 4; ++l) {
        float nh[8];
        #pragma unroll
        for (int j = 0; j < 8; ++j) {
            float acc = 0.f;
            #pragma unroll
            for (int r = 0; r < 8; ++r) acc += h[r] * bf16r(Wh[(l*8 + r)*8 + j]);
            float t = bf16r(acc);
            t = bf16r(t + bf16r(bh[l*8 + j]));
            float s = bf16r(sinf(t));
            nh[j] = bf16r(h[j] + s);
        }
        #pragma unroll
        for (int j = 0; j < 8; ++j) h[j] = nh[j];
    }
    #pragma unroll
    for (int j = 0; j < 8; ++j) hout[b*8 + j] = h[j];
}

__global__ __launch_bounds__(256) void hist_rank_kernel(const int* __restrict__ inds,
                                                        unsigned* __restrict__ hist,
                                                        unsigned* __restrict__ rank) {
    int n = blockIdx.x * 256 + threadIdx.x;
    if (n >= NPTS) return;
    rank[n] = atomicAdd(&hist[inds[n*3]*VOL + inds[n*3+1]], 1u);
}

// Multi-block scan over 16384 bins: A (per-wg sums), B (prefix of 64), C (final).
__global__ __launch_bounds__(256) void scanA_kernel(const unsigned* __restrict__ hist,
                                                    unsigned* __restrict__ wgsum) {
    __shared__ unsigned s[256];
    int t = threadIdx.x;
    s[t] = hist[blockIdx.x * 256 + t];
    __syncthreads();
    for (int off = 128; off > 0; off >>= 1) {
        if (t < off) s[t] += s[t + off];
        __syncthreads();
    }
    if (t == 0) wgsum[blockIdx.x] = s[0];
}
__global__ __launch_bounds__(64) void scanB_kernel(unsigned* __restrict__ wgsum,
                                                   unsigned* __restrict__ binstart,
                                                   unsigned* __restrict__ ctrl) {
    if (threadIdx.x == 0) {
        unsigned run = 0;
        for (int i = 0; i < 64; ++i) { unsigned v = wgsum[i]; wgsum[i] = run; run += v; }
        binstart[NBINS] = run;
        ctrl[0] = 0u; ctrl[1] = 0u;
    }
}
__global__ __launch_bounds__(256) void scanC_kernel(const unsigned* __restrict__ hist,
                                                    const unsigned* __restrict__ wgsum,
                                                    unsigned* __restrict__ binstart) {
    __shared__ unsigned s[256];
    int t = threadIdx.x;
    int idx = blockIdx.x * 256 + t;
    unsigned h = hist[idx];
    s[t] = h; __syncthreads();
    for (int off = 1; off < 256; off <<= 1) {
        unsigned v = (t >= off) ? s[t - off] : 0u;
        __syncthreads();
        s[t] += v;
        __syncthreads();
    }
    binstart[idx] = s[t] - h + wgsum[blockIdx.x];
}

// Per point: all 8 batch entries packed into one 64B record at coords_c[pos].
// Entry (ushort4): x=(cx+8)*256, y/z=(c-ind+2)*8192, w=f16(val); far: y=0xFFFF,
// exact float4 to farbuf with cz biased by 256*b.
__global__ __launch_bounds__(256) void coords_kernel(
    const float* __restrict__ Wf, const float* __restrict__ bfv_g,
    const float* __restrict__ rv, const int* __restrict__ inds,
    const float* __restrict__ hbuf, const unsigned* __restrict__ binstart,
    const unsigned* __restrict__ rank,
    unsigned* __restrict__ ctrl, float4* __restrict__ farbuf,
    uint4* __restrict__ coords_c)
{
    __shared__ float hs[64];
    if (threadIdx.x < 64) hs[threadIdx.x] = hbuf[threadIdx.x];
    __syncthreads();
    int n = blockIdx.x * 256 + threadIdx.x;
    if (n >= NPTS) return;
    int iz = inds[n*3], iy = inds[n*3+1], ix = inds[n*3+2];
    float cnx = ((float)ix - FACTORF) / FACTORF;
    float cny = ((float)iy - FACTORF) / FACTORF;
    float cnz = ((float)iz - FACTORF) / FACTORF;
    float val0 = rv[n];
    float4 bfv = ((const float4*)bfv_g)[n];
    float4 wf[8];
    #pragma unroll
    for (int r = 0; r < 8; ++r)
        wf[r] = ((const float4*)(Wf + (size_t)r * 4 * NPTS))[n];
    unsigned pos = binstart[iz*VOL + iy] + rank[n];
    unsigned ew[16];   // 8 entries x (lo,hi) words
    #pragma unroll
    for (int b = 0; b < BATCH; ++b) {
        float o0 = bfv.x, o1 = bfv.y, o2 = bfv.z, o3 = bfv.w;
        #pragma unroll
        for (int r = 0; r < 8; ++r) {
            float hv = hs[b*8 + r];
            o0 = fmaf(hv, wf[r].x, o0);
            o1 = fmaf(hv, wf[r].y, o1);
            o2 = fmaf(hv, wf[r].z, o2);
            o3 = fmaf(hv, wf[r].w, o3);
        }
        float cx = FACTORF * (cnx + o0) + FACTORF;
        float cy = FACTORF * (cny + o1) + FACTORF;
        float cz = FACTORF * (cnz + o2) + FACTORF;
        float val = val0 + o3;
        int bz = (int)floorf(cz), by = (int)floorf(cy);
        bool nearzy = ((unsigned)(bz - iz + 2) <= 4u) &&
                      ((unsigned)(by - iy + 2) <= 4u);
        if (nearzy) {
            unsigned ex = (unsigned)fminf(fmaxf(fmaf(cx + 8.f, 256.f, 0.5f), 0.f), 65535.f);
            unsigned ey = (unsigned)fminf(fmaf(cy - (float)iy + 2.f, 8192.f, 0.5f), 40959.f);
            unsigned ez = (unsigned)fminf(fmaf(cz - (float)iz + 2.f, 8192.f, 0.5f), 40959.f);
            ew[b*2]   = ex | (ey << 16);
            ew[b*2+1] = ez | (f16bits(val) << 16);
        } else {
            ew[b*2]   = 0xFFFF0000u;
            ew[b*2+1] = 0u;
            unsigned fp = atomicAdd(&ctrl[0], 1u);
            if (fp < FAR_CAP)
                farbuf[fp] = make_float4(cx, cy, cz + 256.0f * (float)b, val);
        }
    }
    uint4* dst = coords_c + (size_t)pos * 4;
    #pragma unroll
    for (int k = 0; k < 4; ++k)
        dst[k] = make_uint4(ew[k*4], ew[k*4+1], ew[k*4+2], ew[k*4+3]);
}

// One wg = (batch-group of 4, RZ x RY x 128 region). One 32B gather serves
// 4 batches; integer pre-filter from quantized fields; 4 LDS tiles.
__global__ __launch_bounds__(256) void region_kernel(
    const uint4* __restrict__ coords_c,
    const unsigned* __restrict__ binstart, float* __restrict__ out)
{
    __shared__ float tile[BG*RZ*RY*VOL];          // 64 KB
    __shared__ unsigned rstart[NRANGE];
    __shared__ unsigned rcum[NRANGE+1];
    __shared__ short rpz[NRANGE], rpy[NRANGE];
    int tid = threadIdx.x;
    int bg  = blockIdx.x >> 9;                     // 0..1
    int rid = blockIdx.x & 511;
    int z0 = (rid >> 5) * RZ, y0 = (rid & 31) * RY;

    for (int i = tid; i < BG*RZ*RY*VOL; i += 256) tile[i] = 0.f;

    if (tid < NRANGE) {
        int zi = tid / HALO_Y, yi = tid - zi * HALO_Y;
        int zz = (z0 - 3 + zi) & (VOL-1);
        int yy = (y0 - 3 + yi) & (VOL-1);
        int base = zz * VOL + yy;
        unsigned s = binstart[base];
        rstart[tid] = s;
        rpz[tid] = (short)zz; rpy[tid] = (short)yy;
        rcum[tid+1] = binstart[base+1] - s;
    }
    if (tid == 0) rcum[0] = 0u;
    __syncthreads();
    for (int off = 1; off < NRANGE; off <<= 1) {
        unsigned v = 0u;
        if (tid < NRANGE && tid >= off) v = rcum[tid+1-off];
        __syncthreads();
        if (tid < NRANGE && tid >= off) rcum[tid+1] += v;
        __syncthreads();
    }
    unsigned total = rcum[NRANGE];

    const int ox[8] = {0,1,0,0,0,1,1,1};
    const int oy[8] = {0,0,1,0,1,0,1,1};
    const int oz[8] = {0,0,0,1,1,1,0,1};

    int r = 0;
    for (unsigned f = tid; f < total; f += 512u) {
        uint4 qa[2], qb[2]; int pz[2], py[2]; bool v[2];
        #pragma unroll
        for (int u = 0; u < 2; ++u) {
            unsigned fu = f + (unsigned)u * 256u;
            v[u] = fu < total;
            if (v[u]) {
                while (fu >= rcum[r+1]) ++r;
                unsigned j = rstart[r] + (fu - rcum[r]);
                const uint4* src = coords_c + (size_t)j * 4 + (size_t)bg * 2;
                qa[u] = src[0];
                qb[u] = src[1];
                pz[u] = rpz[r]; py[u] = rpy[r];
            }
        }
        #pragma unroll
        for (int u = 0; u < 2; ++u) {
            if (!v[u]) continue;
            int piz = pz[u], piy = py[u];
            unsigned w0[4] = {qa[u].x, qa[u].z, qb[u].x, qb[u].z};
            unsigned w1[4] = {qa[u].y, qa[u].w, qb[u].y, qb[u].w};
            #pragma unroll
            for (int e = 0; e < 4; ++e) {
                unsigned lo = w0[e], hi = w1[e];
                unsigned ey = lo >> 16;
                if (ey == 0xFFFFu) continue;
                unsigned ez = hi & 0xFFFFu;
                // integer pre-filter: decoded floor deltas
                int bz = piz + (int)(ez >> 13) - 2;
                int by = piy + (int)(ey >> 13) - 2;
                int dz0 = (bz - z0) & 127, dz1 = (bz + 1 - z0) & 127;
                if (dz0 >= RZ && dz1 >= RZ) continue;
                int dy0 = (by - y0) & 127, dy1 = (by + 1 - y0) & 127;
                if (dy0 >= RY && dy1 >= RY) continue;
                float cx = (float)(lo & 0xFFFFu) * (1.f/256.f) - 8.f;
                float cy = (float)piy + (float)ey * (1.f/8192.f) - 2.f;
                float cz = (float)piz + (float)ez * (1.f/8192.f) - 2.f;
                float val = f16val(hi >> 16);
                float fxf = floorf(cx), fyf = floorf(cy), fzf = floorf(cz);
                int bx = (int)fxf;
                float fx = cx - fxf, fy = cy - fyf, fz = cz - fzf;
                float gx = 1.f - fx, gy = 1.f - fy, gz = 1.f - fz;
                float w[8] = {gx*gy*gz, fx*gy*gz, gx*fy*gz, gx*gy*fz,
                              gx*fy*fz, fx*gy*fz, fx*fy*gz, fx*fy*fz};
                float* tb = tile + (e << 12);
                #pragma unroll
                for (int o = 0; o < 8; ++o) {
                    int dz = (bz + oz[o] - z0) & 127;
                    if (dz >= RZ) continue;
                    int dy = (by + oy[o] - y0) & 127;
                    if (dy >= RY) continue;
                    int X = (bx + ox[o]) & 127;
                    atomicAdd(&tb[(dz << 9) + (dy << 7) + X], val * w[o]);
                }
            }
        }
    }
    __syncthreads();
    for (int i = tid; i < BG*RZ*RY*VOL; i += 256) {
        int bgl = i >> 12;
        int rem = i & 4095;
        int lz = rem >> 9, ly = (rem >> 7) & (RY-1), lx = rem & 127;
        out[(size_t)(bg*BG + bgl) * V3 + (size_t)(z0+lz)*V2 + (y0+ly)*VOL + lx]
            = tile[i];
    }
}

// Far entries: cz carries 256*b bias.
__global__ __launch_bounds__(256) void far_kernel(
    const unsigned* __restrict__ ctrl, const float4* __restrict__ farbuf,
    float* __restrict__ out)
{
    unsigned cnt = ctrl[0];
    if (cnt > FAR_CAP) cnt = FAR_CAP;
    const int ox[8] = {0,1,0,0,0,1,1,1};
    const int oy[8] = {0,0,1,0,1,0,1,1};
    const int oz[8] = {0,0,0,1,1,1,0,1};
    for (unsigned idx = blockIdx.x * 256 + threadIdx.x; idx < cnt;
         idx += gridDim.x * 256) {
        float4 c = farbuf[idx];
        int b = (int)floorf((c.z + 8.0f) * (1.0f/256.0f));
        float cz = c.z - 256.0f * (float)b;
        float fxf = floorf(c.x), fyf = floorf(c.y), fzf = floorf(cz);
        int bx = (int)fxf, by = (int)fyf, bz = (int)fzf;
        float fx = c.x - fxf, fy = c.y - fyf, fz = cz - fzf;
        float gx = 1.f - fx, gy = 1.f - fy, gz = 1.f - fz;
        float val = c.w;
        float w[8] = {gx*gy*gz, fx*gy*gz, gx*fy*gz, gx*gy*fz,
                      gx*fy*fz, fx*gy*fz, fx*fy*gz, fx*fy*fz};
        float* ob = out + (size_t)b * V3;
        #pragma unroll
        for (int o = 0; o < 8; ++o) {
            int Z = (bz + oz[o]) & (VOL-1);
            int Y = (by + oy[o]) & (VOL-1);
            int X = (bx + ox[o]) & (VOL-1);
            atomicAdd(ob + (size_t)Z*V2 + Y*VOL + X, val * w[o]);
        }
    }
}

// Fallback (round-11 verified path) if workspace too small.
__global__ __launch_bounds__(256) void scatter_fallback(
    const float* __restrict__ Wf, const float* __restrict__ bfv_g,
    const float* __restrict__ rv, const int* __restrict__ inds,
    const float* __restrict__ hbuf, float* __restrict__ out)
{
    __shared__ float hs[BATCH*8];
    if (threadIdx.x < BATCH*8) hs[threadIdx.x] = hbuf[threadIdx.x];
    __syncthreads();
    int n = blockIdx.x * blockDim.x + threadIdx.x;
    if (n >= NPTS) return;
    int iz = inds[n*3 + 0], iy = inds[n*3 + 1], ix = inds[n*3 + 2];
    float cnx = ((float)ix - FACTORF) / FACTORF;
    float cny = ((float)iy - FACTORF) / FACTORF;
    float cnz = ((float)iz - FACTORF) / FACTORF;
    float val0 = rv[n];
    float4 bfv = ((const float4*)bfv_g)[n];
    float4 wf[8];
    #pragma unroll
    for (int r = 0; r < 8; ++r)
        wf[r] = ((const float4*)(Wf + (size_t)r * 4 * NPTS))[n];
    static const int offs[8][3] = {{0,0,0},{1,0,0},{0,1,0},{0,0,1},
                                   {0,1,1},{1,0,1},{1,1,0},{1,1,1}};
    #pragma unroll
    for (int b = 0; b < BATCH; ++b) {
        float o0 = bfv.x, o1 = bfv.y, o2 = bfv.z, o3 = bfv.w;
        #pragma unroll
        for (int r = 0; r < 8; ++r) {
            float hv = hs[b*8 + r];
            o0 = fmaf(hv, wf[r].x, o0);
            o1 = fmaf(hv, wf[r].y, o1);
            o2 = fmaf(hv, wf[r].z, o2);
            o3 = fmaf(hv, wf[r].w, o3);
        }
        float cx = FACTORF * (cnx + o0) + FACTORF;
        float cy = FACTORF * (cny + o1) + FACTORF;
        float cz = FACTORF * (cnz + o2) + FACTORF;
        float val = val0 + o3;
        float fxf = floorf(cx), fyf = floorf(cy), fzf = floorf(cz);
        int bx = (int)fxf, by = (int)fyf, bz = (int)fzf;
        float fx = cx - fxf, fy = cy - fyf, fz = cz - fzf;
        float gx = 1.f - fx, gy = 1.f - fy, gz = 1.f - fz;
        float w[8] = {gx*gy*gz, fx*gy*gz, gx*fy*gz, gx*gy*fz,
                      gx*fy*fz, fx*gy*fz, fx*fy*gz, fx*fy*fz};
        float* ob = out + (size_t)b * V3;
        #pragma unroll
        for (int o = 0; o < 8; ++o) {
            int X = (bx + offs[o][0]) & (VOL-1);
            int Y = (by + offs[o][1]) & (VOL-1);
            int Z = (bz + offs[o][2]) & (VOL-1);
            atomicAdd(ob + (size_t)Z*V2 + Y*VOL + X, val * w[o]);
        }
    }
}

extern "C" void kernel_launch(void* const* d_in, const int* in_sizes, int n_in,
                              void* d_out, int out_size, void* d_ws, size_t ws_size,
                              hipStream_t stream) {
    const float* x    = (const float*)d_in[0];
    const float* W0   = (const float*)d_in[1];
    const float* b0   = (const float*)d_in[2];
    const float* Wh   = (const float*)d_in[3];
    const float* bh   = (const float*)d_in[4];
    const float* Wf   = (const float*)d_in[5];
    const float* bf   = (const float*)d_in[6];
    const float* rv   = (const float*)d_in[7];
    const int*   inds = (const int*)d_in[8];
    float* out = (float*)d_out;
    char*  ws  = (char*)d_ws;

    float*    hbuf     = (float*)(ws + WS_HBUF);
    unsigned* hist     = (unsigned*)(ws + WS_HIST);
    unsigned* binstart = (unsigned*)(ws + WS_START);
    unsigned* rank     = (unsigned*)(ws + WS_RANK);
    unsigned* ctrl     = (unsigned*)(ws + WS_CTRL);
    unsigned* wgsum    = (unsigned*)(ws + WS_WGSUM);
    float4*   farbuf   = (float4*)(ws + WS_FARBUF);
    uint4*    coords_c = (uint4*)(ws + WS_COORDC);

    mlp_kernel<<<1, 64, 0, stream>>>(x, W0, b0, Wh, bh, hbuf);

    if (ws_size >= (size_t)WS_FULL) {
        hipMemsetAsync(hist, 0, NBINS*4, stream);
        hist_rank_kernel<<<NPTS/256, 256, 0, stream>>>(inds, hist, rank);
        scanA_kernel<<<64, 256, 0, stream>>>(hist, wgsum);
        scanB_kernel<<<1, 64, 0, stream>>>(wgsum, binstart, ctrl);
        scanC_kernel<<<64, 256, 0, stream>>>(hist, wgsum, binstart);
        coords_kernel<<<NPTS/256, 256, 0, stream>>>(Wf, bf, rv, inds, hbuf,
                                                    binstart, rank,
                                                    ctrl, farbuf, coords_c);
        region_kernel<<<512*(BATCH/BG), 256, 0, stream>>>(coords_c, binstart, out);
        far_kernel<<<8, 256, 0, stream>>>(ctrl, farbuf, out);
    } else {
        hipMemsetAsync(d_out, 0, (size_t)out_size * sizeof(float), stream);
        scatter_fallback<<<NPTS/256, 256, 0, stream>>>(Wf, bf, rv, inds, hbuf, out);
    }
}